// Round 2
// baseline (428.486 us; speedup 1.0000x reference)
//
#include <hip/hip_runtime.h>
#include <hip/hip_bf16.h>

#define NN 2048
#define BB 8
#define FD 256
#define NEG_SLOPE 0.2f
#define EPSV 1e-7f

typedef __bf16 bf16x8 __attribute__((ext_vector_type(8)));
typedef __bf16 bf16x4 __attribute__((ext_vector_type(4)));
typedef float f32x4 __attribute__((ext_vector_type(4)));

// K1: WT[o][f] = bf16(W[f][o]); zero den; zero out (for K6 atomic accumulation)
__global__ __launch_bounds__(256) void k1_prep(const float* __restrict__ W,
                                               __bf16* __restrict__ WT,
                                               float* __restrict__ den,
                                               float4* __restrict__ out4) {
    int idx = blockIdx.x * 256 + threadIdx.x;
    if (idx < FD * FD) {
        int o = idx >> 8, f = idx & 255;
        WT[idx] = (__bf16)W[f * FD + o];
    }
    if (idx < BB * NN) den[idx] = 0.f;
    // out has BB*NN*FD = 4,194,304 floats = 1,048,576 float4 = 4096 blocks * 256
    out4[idx] = (float4){0.f, 0.f, 0.f, 0.f};
}

// K2: Wh = x @ W  (bf16 MFMA, fp32 out). wave = 16 rows x 128 cols.
__global__ __launch_bounds__(256) void k2_whgemm(const float* __restrict__ x,
                                                 const __bf16* __restrict__ WT,
                                                 float* __restrict__ Wh) {
    const int wave = threadIdx.x >> 6;
    const int lane = threadIdx.x & 63;
    const int row0 = blockIdx.x * 32 + (wave >> 1) * 16;
    const int ohalf = (wave & 1) * 128;
    const int m = lane & 15;
    const int quad = lane >> 4;
    const int row = row0 + m;
    const float* xrow = x + (size_t)row * FD + quad * 8;

    f32x4 acc[8];
#pragma unroll
    for (int n = 0; n < 8; ++n) acc[n] = (f32x4){0.f, 0.f, 0.f, 0.f};

    for (int k0 = 0; k0 < FD; k0 += 32) {
        float4 xa = *(const float4*)(xrow + k0);
        float4 xb = *(const float4*)(xrow + k0 + 4);
        bf16x8 af;
        af[0] = (__bf16)xa.x; af[1] = (__bf16)xa.y; af[2] = (__bf16)xa.z; af[3] = (__bf16)xa.w;
        af[4] = (__bf16)xb.x; af[5] = (__bf16)xb.y; af[6] = (__bf16)xb.z; af[7] = (__bf16)xb.w;
#pragma unroll
        for (int n = 0; n < 8; ++n) {
            int o = ohalf + n * 16 + m;
            bf16x8 bf = *(const bf16x8*)(WT + o * FD + k0 + quad * 8);
            acc[n] = __builtin_amdgcn_mfma_f32_16x16x32_bf16(af, bf, acc[n], 0, 0, 0);
        }
    }
#pragma unroll
    for (int n = 0; n < 8; ++n) {
        int o = ohalf + n * 16 + m;
#pragma unroll
        for (int r = 0; r < 4; ++r) {
            Wh[(size_t)(row0 + quad * 4 + r) * FD + o] = acc[n][r];
        }
    }
}

// K3: s_src[row] = Wh[row]·a_w[0:256], s_dst[row] = Wh[row]·a_w[256:512]
__global__ __launch_bounds__(256) void k3_scores(const float* __restrict__ Wh,
                                                 const float* __restrict__ a_w,
                                                 float* __restrict__ s_src,
                                                 float* __restrict__ s_dst) {
    int wave = threadIdx.x >> 6, lane = threadIdx.x & 63;
    int row = blockIdx.x * 4 + wave;
    float4 wv = *(const float4*)(Wh + (size_t)row * FD + lane * 4);
    float4 a0 = *(const float4*)(a_w + lane * 4);
    float4 a1 = *(const float4*)(a_w + FD + lane * 4);
    float d0 = wv.x * a0.x + wv.y * a0.y + wv.z * a0.z + wv.w * a0.w;
    float d1 = wv.x * a1.x + wv.y * a1.y + wv.z * a1.z + wv.w * a1.w;
#pragma unroll
    for (int off = 32; off; off >>= 1) {
        d0 += __shfl_down(d0, off, 64);
        d1 += __shfl_down(d1, off, 64);
    }
    if (lane == 0) { s_src[row] = d0; s_dst[row] = d1; }
}

// K4: den[b][j] += sum_i A[b][i][j] * exp(lrelu(s_src[i]+s_dst[j]+ab))
// 1D grid: b = blk&7 (XCD affinity), then 128 i-splits x 2 j-splits. 2048 blocks.
__global__ __launch_bounds__(256) void k4_den(const float* __restrict__ A,
                                              const float* __restrict__ s_src,
                                              const float* __restrict__ s_dst,
                                              const float* __restrict__ a_bp,
                                              float* __restrict__ den) {
    const int blk = blockIdx.x;
    const int b = blk & 7;
    const int r = blk >> 3;
    const int isplit = r & 127;
    const int jsplit = r >> 7;
    const int i0 = isplit * 16;
    const int j = jsplit * 1024 + threadIdx.x * 4;
    __shared__ float ss[16];
    if (threadIdx.x < 16) ss[threadIdx.x] = s_src[b * NN + i0 + threadIdx.x] + a_bp[0];
    __syncthreads();
    float4 sd = *(const float4*)(s_dst + b * NN + j);
    float ax = 0.f, ay = 0.f, az = 0.f, aw = 0.f;
    const float* Ap = A + ((size_t)b * NN + i0) * NN + j;
#pragma unroll
    for (int i = 0; i < 16; ++i) {
        float4 a = *(const float4*)(Ap + (size_t)i * NN);
        float si = ss[i];
        float e0 = si + sd.x; e0 = e0 > 0.f ? e0 : NEG_SLOPE * e0;
        float e1 = si + sd.y; e1 = e1 > 0.f ? e1 : NEG_SLOPE * e1;
        float e2 = si + sd.z; e2 = e2 > 0.f ? e2 : NEG_SLOPE * e2;
        float e3 = si + sd.w; e3 = e3 > 0.f ? e3 : NEG_SLOPE * e3;
        ax += a.x * __expf(e0);
        ay += a.y * __expf(e1);
        az += a.z * __expf(e2);
        aw += a.w * __expf(e3);
    }
    atomicAdd(&den[b * NN + j + 0], ax);
    atomicAdd(&den[b * NN + j + 1], ay);
    atomicAdd(&den[b * NN + j + 2], az);
    atomicAdd(&den[b * NN + j + 3], aw);
}

// K5: WhT[b][o][j] = bf16( Wh[b][j][o] / (den[b][j]+eps) )
__global__ __launch_bounds__(256) void k5_wht(const float* __restrict__ Wh,
                                              const float* __restrict__ den,
                                              __bf16* __restrict__ WhT) {
    const int b = blockIdx.z;
    const int j0 = blockIdx.x * 64;
    const int o0 = blockIdx.y * 64;
    __shared__ float tile[64][65];
    __shared__ float invd[64];
    if (threadIdx.x < 64) invd[threadIdx.x] = 1.f / (den[b * NN + j0 + threadIdx.x] + EPSV);
    __syncthreads();
    int jr = threadIdx.x >> 4, oc = (threadIdx.x & 15) * 4;
#pragma unroll
    for (int p = 0; p < 4; ++p) {
        int j = jr + p * 16;
        float4 v = *(const float4*)(Wh + (size_t)(b * NN + j0 + j) * FD + o0 + oc);
        float s = invd[j];
        tile[j][oc + 0] = v.x * s;
        tile[j][oc + 1] = v.y * s;
        tile[j][oc + 2] = v.z * s;
        tile[j][oc + 3] = v.w * s;
    }
    __syncthreads();
    int ow = threadIdx.x >> 4, jc = (threadIdx.x & 15) * 4;
#pragma unroll
    for (int p = 0; p < 4; ++p) {
        int o = ow + p * 16;
        bf16x4 w;
        w[0] = (__bf16)tile[jc + 0][o];
        w[1] = (__bf16)tile[jc + 1][o];
        w[2] = (__bf16)tile[jc + 2][o];
        w[3] = (__bf16)tile[jc + 3][o];
        *(bf16x4*)(WhT + (size_t)(b * FD + o0 + o) * NN + j0 + jc) = w;
    }
}

// K6: out[b][i][o] += sum_{j in split} (A*exp(lrelu(e)))[i][j] * WhT'[o][j]
// 1D grid: b = blk&7 (XCD affinity: WhT[b] = 1MB stays in that XCD's L2),
// 64 rowtiles x 4 j-splits. 2048 blocks, fp32 atomic partials into out.
__global__ __launch_bounds__(256) void k6_out(const float* __restrict__ A,
                                              const __bf16* __restrict__ WhT,
                                              const float* __restrict__ s_src,
                                              const float* __restrict__ s_dst,
                                              const float* __restrict__ a_bp,
                                              float* __restrict__ out) {
    const int blk = blockIdx.x;
    const int b = blk & 7;
    const int rr_ = blk >> 3;
    const int rowtile = rr_ & 63;
    const int jsplit = rr_ >> 6;
    const int wave = threadIdx.x >> 6;
    const int lane = threadIdx.x & 63;
    const int i0 = rowtile * 32 + (wave >> 1) * 16;
    const int ohalf = (wave & 1) * 128;
    const int m = lane & 15;
    const int quad = lane >> 4;
    const int row = i0 + m;
    const float ab = a_bp[0];
    const float ssr = s_src[b * NN + row] + ab;
    const int jbase = jsplit * 512;
    const float* Arow = A + ((size_t)b * NN + row) * NN + jbase + quad * 8;
    const float* sdp = s_dst + b * NN + jbase + quad * 8;
    const __bf16* Bbase = WhT + (size_t)(b * FD + ohalf + m) * NN + jbase + quad * 8;

    f32x4 acc[8];
#pragma unroll
    for (int n = 0; n < 8; ++n) acc[n] = (f32x4){0.f, 0.f, 0.f, 0.f};

    // software-pipelined: prefetch next iteration's A + s_dst while MFMAing current
    float4 a0 = *(const float4*)(Arow);
    float4 a1 = *(const float4*)(Arow + 4);
    float4 s0 = *(const float4*)(sdp);
    float4 s1 = *(const float4*)(sdp + 4);
#pragma unroll
    for (int it = 0; it < 16; ++it) {
        float4 ca0 = a0, ca1 = a1, cs0 = s0, cs1 = s1;
        if (it < 15) {
            const float* An = Arow + (it + 1) * 32;
            const float* Sn = sdp + (it + 1) * 32;
            a0 = *(const float4*)(An);
            a1 = *(const float4*)(An + 4);
            s0 = *(const float4*)(Sn);
            s1 = *(const float4*)(Sn + 4);
        }
        bf16x8 af;
        float e;
        e = ssr + cs0.x; e = e > 0.f ? e : NEG_SLOPE * e; af[0] = (__bf16)(ca0.x * __expf(e));
        e = ssr + cs0.y; e = e > 0.f ? e : NEG_SLOPE * e; af[1] = (__bf16)(ca0.y * __expf(e));
        e = ssr + cs0.z; e = e > 0.f ? e : NEG_SLOPE * e; af[2] = (__bf16)(ca0.z * __expf(e));
        e = ssr + cs0.w; e = e > 0.f ? e : NEG_SLOPE * e; af[3] = (__bf16)(ca0.w * __expf(e));
        e = ssr + cs1.x; e = e > 0.f ? e : NEG_SLOPE * e; af[4] = (__bf16)(ca1.x * __expf(e));
        e = ssr + cs1.y; e = e > 0.f ? e : NEG_SLOPE * e; af[5] = (__bf16)(ca1.y * __expf(e));
        e = ssr + cs1.z; e = e > 0.f ? e : NEG_SLOPE * e; af[6] = (__bf16)(ca1.z * __expf(e));
        e = ssr + cs1.w; e = e > 0.f ? e : NEG_SLOPE * e; af[7] = (__bf16)(ca1.w * __expf(e));
#pragma unroll
        for (int n = 0; n < 8; ++n) {
            bf16x8 bf = *(const bf16x8*)(Bbase + (size_t)(n * 16) * NN + it * 32);
            acc[n] = __builtin_amdgcn_mfma_f32_16x16x32_bf16(af, bf, acc[n], 0, 0, 0);
        }
    }
#pragma unroll
    for (int n = 0; n < 8; ++n) {
        int o = ohalf + n * 16 + m;
#pragma unroll
        for (int r = 0; r < 4; ++r) {
            atomicAdd(&out[((size_t)b * NN + i0 + quad * 4 + r) * FD + o], acc[n][r]);
        }
    }
}

extern "C" void kernel_launch(void* const* d_in, const int* in_sizes, int n_in,
                              void* d_out, int out_size, void* d_ws, size_t ws_size,
                              hipStream_t stream) {
    const float* A   = (const float*)d_in[0];
    const float* x   = (const float*)d_in[1];
    const float* W   = (const float*)d_in[2];
    const float* a_w = (const float*)d_in[3];
    const float* a_b = (const float*)d_in[4];
    float* out = (float*)d_out;

    char* ws = (char*)d_ws;
    __bf16* WT   = (__bf16*)ws;                                   // 256*256*2      = 131072 B
    float*  Wh   = (float*)(ws + 131072);                         // 16384*256*4    = 16777216 B
    __bf16* WhT  = (__bf16*)(ws + 131072 + 16777216);             // 8*256*2048*2   = 8388608 B
    float*  s_src = (float*)(ws + 131072 + 16777216 + 8388608);   // 16384*4
    float*  s_dst = s_src + 16384;
    float*  den   = s_dst + 16384;

    k1_prep<<<4096, 256, 0, stream>>>(W, WT, den, (float4*)out);
    k2_whgemm<<<512, 256, 0, stream>>>(x, WT, Wh);
    k3_scores<<<4096, 256, 0, stream>>>(Wh, a_w, s_src, s_dst);
    k4_den<<<2048, 256, 0, stream>>>(A, s_src, s_dst, a_b, den);
    k5_wht<<<dim3(32, 4, 8), 256, 0, stream>>>(Wh, den, WhT);
    k6_out<<<2048, 256, 0, stream>>>(A, WhT, s_src, s_dst, a_b, out);
}

// Round 3
// 302.894 us; speedup vs baseline: 1.4146x; 1.4146x over previous
//
#include <hip/hip_runtime.h>
#include <hip/hip_bf16.h>

#define NN 2048
#define BB 8
#define FD 256
#define NEG_SLOPE 0.2f
#define EPSV 1e-7f
#define PSTR 40   // padded row stride (bf16 elems) for P tiles: 2-way banks only

typedef __bf16 bf16x8 __attribute__((ext_vector_type(8)));
typedef __bf16 bf16x4 __attribute__((ext_vector_type(4)));
typedef float f32x4 __attribute__((ext_vector_type(4)));

// ---------------- K1: WT[o][f] = bf16(W[f][o]) ----------------
__global__ __launch_bounds__(256) void k1_prep(const float* __restrict__ W,
                                               __bf16* __restrict__ WT) {
    int idx = blockIdx.x * 256 + threadIdx.x;   // 256 blocks -> 65536 = FD*FD
    int o = idx >> 8, f = idx & 255;
    WT[idx] = (__bf16)W[f * FD + o];
}

// ---------------- K2: Wh = x @ W (bf16 MFMA) ----------------
__global__ __launch_bounds__(256) void k2_whgemm(const float* __restrict__ x,
                                                 const __bf16* __restrict__ WT,
                                                 float* __restrict__ Wh) {
    const int wave = threadIdx.x >> 6;
    const int lane = threadIdx.x & 63;
    const int row0 = blockIdx.x * 32 + (wave >> 1) * 16;
    const int ohalf = (wave & 1) * 128;
    const int m = lane & 15;
    const int quad = lane >> 4;
    const int row = row0 + m;
    const float* xrow = x + (size_t)row * FD + quad * 8;

    f32x4 acc[8];
#pragma unroll
    for (int n = 0; n < 8; ++n) acc[n] = (f32x4){0.f, 0.f, 0.f, 0.f};

    for (int k0 = 0; k0 < FD; k0 += 32) {
        float4 xa = *(const float4*)(xrow + k0);
        float4 xb = *(const float4*)(xrow + k0 + 4);
        bf16x8 af;
        af[0] = (__bf16)xa.x; af[1] = (__bf16)xa.y; af[2] = (__bf16)xa.z; af[3] = (__bf16)xa.w;
        af[4] = (__bf16)xb.x; af[5] = (__bf16)xb.y; af[6] = (__bf16)xb.z; af[7] = (__bf16)xb.w;
#pragma unroll
        for (int n = 0; n < 8; ++n) {
            int o = ohalf + n * 16 + m;
            bf16x8 bf = *(const bf16x8*)(WT + o * FD + k0 + quad * 8);
            acc[n] = __builtin_amdgcn_mfma_f32_16x16x32_bf16(af, bf, acc[n], 0, 0, 0);
        }
    }
#pragma unroll
    for (int n = 0; n < 8; ++n) {
        int o = ohalf + n * 16 + m;
#pragma unroll
        for (int r = 0; r < 4; ++r) {
            Wh[(size_t)(row0 + quad * 4 + r) * FD + o] = acc[n][r];
        }
    }
}

// ---------------- K3: s_src / s_dst ----------------
__global__ __launch_bounds__(256) void k3_scores(const float* __restrict__ Wh,
                                                 const float* __restrict__ a_w,
                                                 float* __restrict__ s_src,
                                                 float* __restrict__ s_dst) {
    int wave = threadIdx.x >> 6, lane = threadIdx.x & 63;
    int row = blockIdx.x * 4 + wave;
    float4 wv = *(const float4*)(Wh + (size_t)row * FD + lane * 4);
    float4 a0 = *(const float4*)(a_w + lane * 4);
    float4 a1 = *(const float4*)(a_w + FD + lane * 4);
    float d0 = wv.x * a0.x + wv.y * a0.y + wv.z * a0.z + wv.w * a0.w;
    float d1 = wv.x * a1.x + wv.y * a1.y + wv.z * a1.z + wv.w * a1.w;
#pragma unroll
    for (int off = 32; off; off >>= 1) {
        d0 += __shfl_down(d0, off, 64);
        d1 += __shfl_down(d1, off, 64);
    }
    if (lane == 0) { s_src[row] = d0; s_dst[row] = d1; }
}

// ---------------- K4: den_part[isp][b][j] = partial column sums (NO atomics) ----
// grid 1024: b = blk&7, jhalf = (blk>>3)&1, isp = blk>>4 (0..63); 32 i x 1024 j per block
__global__ __launch_bounds__(256) void k4_den(const float* __restrict__ A,
                                              const float* __restrict__ s_src,
                                              const float* __restrict__ s_dst,
                                              const float* __restrict__ a_bp,
                                              float* __restrict__ den_part) {
    const int blk = blockIdx.x;
    const int b = blk & 7;
    const int jhalf = (blk >> 3) & 1;
    const int isp = blk >> 4;
    const int i0 = isp * 32;
    const int j = jhalf * 1024 + threadIdx.x * 4;
    __shared__ float ss[32];
    if (threadIdx.x < 32) ss[threadIdx.x] = s_src[b * NN + i0 + threadIdx.x] + a_bp[0];
    __syncthreads();
    float4 sd = *(const float4*)(s_dst + b * NN + j);
    float ax = 0.f, ay = 0.f, az = 0.f, aw = 0.f;
    const float* Ap = A + ((size_t)b * NN + i0) * NN + j;
#pragma unroll 8
    for (int i = 0; i < 32; ++i) {
        float4 a = *(const float4*)(Ap + (size_t)i * NN);
        float si = ss[i];
        float e0 = si + sd.x; e0 = e0 > 0.f ? e0 : NEG_SLOPE * e0;
        float e1 = si + sd.y; e1 = e1 > 0.f ? e1 : NEG_SLOPE * e1;
        float e2 = si + sd.z; e2 = e2 > 0.f ? e2 : NEG_SLOPE * e2;
        float e3 = si + sd.w; e3 = e3 > 0.f ? e3 : NEG_SLOPE * e3;
        ax += a.x * __expf(e0);
        ay += a.y * __expf(e1);
        az += a.z * __expf(e2);
        aw += a.w * __expf(e3);
    }
    float4 r = (float4){ax, ay, az, aw};
    *(float4*)(den_part + (size_t)isp * (BB * NN) + b * NN + j) = r;
}

// ---------------- K5: WhT[b][o][j] = bf16( Wh[b][j][o] / (sum(den_part)+eps) ) ----
__global__ __launch_bounds__(256) void k5_wht(const float* __restrict__ Wh,
                                              const float* __restrict__ den_part,
                                              __bf16* __restrict__ WhT) {
    const int b = blockIdx.z;
    const int j0 = blockIdx.x * 64;
    const int o0 = blockIdx.y * 64;
    __shared__ float tile[64][65];
    __shared__ float invd[64];
    if (threadIdx.x < 64) {
        float s = 0.f;
        const float* dp = den_part + b * NN + j0 + threadIdx.x;
#pragma unroll 8
        for (int sI = 0; sI < 64; ++sI) s += dp[(size_t)sI * (BB * NN)];
        invd[threadIdx.x] = 1.f / (s + EPSV);
    }
    __syncthreads();
    int jr = threadIdx.x >> 4, oc = (threadIdx.x & 15) * 4;
#pragma unroll
    for (int p = 0; p < 4; ++p) {
        int jj = jr + p * 16;
        float4 v = *(const float4*)(Wh + (size_t)(b * NN + j0 + jj) * FD + o0 + oc);
        float s = invd[jj];
        tile[jj][oc + 0] = v.x * s;
        tile[jj][oc + 1] = v.y * s;
        tile[jj][oc + 2] = v.z * s;
        tile[jj][oc + 3] = v.w * s;
    }
    __syncthreads();
    int ow = threadIdx.x >> 4, jc = (threadIdx.x & 15) * 4;
#pragma unroll
    for (int p = 0; p < 4; ++p) {
        int o = ow + p * 16;
        bf16x4 wv;
        wv[0] = (__bf16)tile[jc + 0][o];
        wv[1] = (__bf16)tile[jc + 1][o];
        wv[2] = (__bf16)tile[jc + 2][o];
        wv[3] = (__bf16)tile[jc + 3][o];
        *(bf16x4*)(WhT + (size_t)(b * FD + o0 + o) * NN + j0 + jc) = wv;
    }
}

// ---------------- K6: LDS-tiled fused GEMM: part[jsp] += P @ WhT' ----------------
// 512 blocks: b = blk&7 (XCD affinity), itile = (blk>>3)&15, jsp = blk>>7.
// Block: 128 i x 256 o, 512 threads = 8 waves (2 wrow x 4 wcol), wave = 64i x 64o.
// P (128 x 32 bf16) double-buffered in LDS, built from A on the fly; one barrier/step.
__global__ __launch_bounds__(512, 4) void k6_out(const float* __restrict__ A,
                                                 const __bf16* __restrict__ WhT,
                                                 const float* __restrict__ s_src,
                                                 const float* __restrict__ s_dst,
                                                 const float* __restrict__ a_bp,
                                                 float* __restrict__ part) {
    __shared__ __bf16 P[2][128 * PSTR];   // 2 x 10240 B
    const int blk = blockIdx.x;
    const int b = blk & 7;
    const int r_ = blk >> 3;
    const int itile = r_ & 15;
    const int jsp = r_ >> 4;
    const int i0 = itile * 128;
    const int jbase = jsp * 512;
    const int t = threadIdx.x;
    const int w = t >> 6, lane = t & 63;
    const int wrow = w >> 2, wcol = w & 3;
    const int m = lane & 15, quad = lane >> 4;

    // P-build role: thread builds 8 elements of row prow, cols ps*8..ps*8+7
    const int prow = t >> 2, ps = t & 3;
    const float ssr = s_src[b * NN + i0 + prow] + a_bp[0];
    const float* Abase = A + ((size_t)(b * NN + i0 + prow)) * NN + jbase + ps * 8;
    const float* sdbase = s_dst + b * NN + jbase + ps * 8;
    __bf16* Pw = &P[0][0] + prow * PSTR + ps * 8;

    // prefetch step 0
    float4 a0 = *(const float4*)(Abase);
    float4 a1 = *(const float4*)(Abase + 4);
    float4 q0 = *(const float4*)(sdbase);
    float4 q1 = *(const float4*)(sdbase + 4);

#define BUILD_P(dstbuf)                                                          \
    {                                                                            \
        bf16x8 wv; float e;                                                      \
        e = ssr + q0.x; e = e > 0.f ? e : NEG_SLOPE * e; wv[0] = (__bf16)(a0.x * __expf(e)); \
        e = ssr + q0.y; e = e > 0.f ? e : NEG_SLOPE * e; wv[1] = (__bf16)(a0.y * __expf(e)); \
        e = ssr + q0.z; e = e > 0.f ? e : NEG_SLOPE * e; wv[2] = (__bf16)(a0.z * __expf(e)); \
        e = ssr + q0.w; e = e > 0.f ? e : NEG_SLOPE * e; wv[3] = (__bf16)(a0.w * __expf(e)); \
        e = ssr + q1.x; e = e > 0.f ? e : NEG_SLOPE * e; wv[4] = (__bf16)(a1.x * __expf(e)); \
        e = ssr + q1.y; e = e > 0.f ? e : NEG_SLOPE * e; wv[5] = (__bf16)(a1.y * __expf(e)); \
        e = ssr + q1.z; e = e > 0.f ? e : NEG_SLOPE * e; wv[6] = (__bf16)(a1.z * __expf(e)); \
        e = ssr + q1.w; e = e > 0.f ? e : NEG_SLOPE * e; wv[7] = (__bf16)(a1.w * __expf(e)); \
        *(bf16x8*)(Pw + (dstbuf) * (128 * PSTR)) = wv;                           \
    }

    BUILD_P(0)   // P(0) -> buf0

    f32x4 acc[4][4];
#pragma unroll
    for (int r = 0; r < 4; ++r)
#pragma unroll
        for (int n = 0; n < 4; ++n) acc[r][n] = (f32x4){0.f, 0.f, 0.f, 0.f};

    const __bf16* Bbase = WhT + (size_t)(b * FD + wcol * 64 + m) * NN + jbase + quad * 8;
    const __bf16* Prd = &P[0][0] + (wrow * 64 + m) * PSTR + quad * 8;

    for (int kk = 0; kk < 16; ++kk) {
        __syncthreads();   // P(kk) written by all; previous buf's reads complete
        if (kk < 15) {     // prefetch A/sd for step kk+1 (consumed after MFMA phase)
            const float* An = Abase + (kk + 1) * 32;
            const float* Sn = sdbase + (kk + 1) * 32;
            a0 = *(const float4*)(An);
            a1 = *(const float4*)(An + 4);
            q0 = *(const float4*)(Sn);
            q1 = *(const float4*)(Sn + 4);
        }
        const __bf16* Pk = Prd + (kk & 1) * (128 * PSTR);
        bf16x8 af[4];
#pragma unroll
        for (int r = 0; r < 4; ++r) af[r] = *(const bf16x8*)(Pk + r * 16 * PSTR);
#pragma unroll
        for (int n = 0; n < 4; ++n) {
            bf16x8 bfr = *(const bf16x8*)(Bbase + (size_t)(n * 16) * NN + kk * 32);
#pragma unroll
            for (int r = 0; r < 4; ++r)
                acc[r][n] = __builtin_amdgcn_mfma_f32_16x16x32_bf16(af[r], bfr, acc[r][n], 0, 0, 0);
        }
        if (kk < 15) BUILD_P((kk + 1) & 1)
    }

    float* pout = part + (size_t)jsp * (BB * NN * FD);
#pragma unroll
    for (int r = 0; r < 4; ++r) {
#pragma unroll
        for (int n = 0; n < 4; ++n) {
            int o = wcol * 64 + n * 16 + m;
#pragma unroll
            for (int rr = 0; rr < 4; ++rr) {
                int row = i0 + wrow * 64 + r * 16 + quad * 4 + rr;
                pout[(size_t)(b * NN + row) * FD + o] = acc[r][n][rr];
            }
        }
    }
#undef BUILD_P
}

// ---------------- K7: out = sum of 4 jsplit partials ----------------
__global__ __launch_bounds__(256) void k7_reduce(const float4* __restrict__ part4,
                                                 float4* __restrict__ out4) {
    int idx = blockIdx.x * 256 + threadIdx.x;   // 4096 blocks -> 1,048,576 float4
    float4 a = part4[idx];
    float4 b2 = part4[idx + 1048576];
    float4 c = part4[idx + 2097152];
    float4 d = part4[idx + 3145728];
    float4 r;
    r.x = a.x + b2.x + c.x + d.x;
    r.y = a.y + b2.y + c.y + d.y;
    r.z = a.z + b2.z + c.z + d.z;
    r.w = a.w + b2.w + c.w + d.w;
    out4[idx] = r;
}

extern "C" void kernel_launch(void* const* d_in, const int* in_sizes, int n_in,
                              void* d_out, int out_size, void* d_ws, size_t ws_size,
                              hipStream_t stream) {
    const float* A   = (const float*)d_in[0];
    const float* x   = (const float*)d_in[1];
    const float* W   = (const float*)d_in[2];
    const float* a_w = (const float*)d_in[3];
    const float* a_b = (const float*)d_in[4];
    float* out = (float*)d_out;

    char* ws = (char*)d_ws;
    __bf16* WT      = (__bf16*)ws;                      // 131,072 B
    float*  Wh      = (float*)(ws + 131072);            // 16,777,216 B
    __bf16* WhT     = (__bf16*)(ws + 16908288);         // 8,388,608 B
    float*  s_src   = (float*)(ws + 25296896);          // 65,536 B
    float*  s_dst   = (float*)(ws + 25362432);          // 65,536 B
    float*  den_part= (float*)(ws + 25427968);          // 64*16384*4 = 4,194,304 B
    float*  part    = (float*)(ws + 29622272);          // 4*16,777,216 = 67,108,864 B
                                                        // total = 96,731,136 B

    k1_prep<<<256, 256, 0, stream>>>(W, WT);
    k2_whgemm<<<512, 256, 0, stream>>>(x, WT, Wh);
    k3_scores<<<4096, 256, 0, stream>>>(Wh, a_w, s_src, s_dst);
    k4_den<<<1024, 256, 0, stream>>>(A, s_src, s_dst, a_b, den_part);
    k5_wht<<<dim3(32, 4, 8), 256, 0, stream>>>(Wh, den_part, WhT);
    k6_out<<<512, 512, 0, stream>>>(A, WhT, s_src, s_dst, a_b, part);
    k7_reduce<<<4096, 256, 0, stream>>>((const float4*)part, (float4*)out);
}

// Round 4
// 298.744 us; speedup vs baseline: 1.4343x; 1.0139x over previous
//
#include <hip/hip_runtime.h>
#include <hip/hip_bf16.h>

#define NN 2048
#define BB 8
#define FD 256
#define NEG_SLOPE 0.2f
#define EPSV 1e-7f

typedef __bf16 bf16x8 __attribute__((ext_vector_type(8)));
typedef __bf16 bf16x4 __attribute__((ext_vector_type(4)));
typedef float f32x4 __attribute__((ext_vector_type(4)));

// async 16B global -> LDS (dest = wave-uniform base + lane*16)
__device__ __forceinline__ void gload16(const __bf16* g, __bf16* l) {
    __builtin_amdgcn_global_load_lds((const __attribute__((address_space(1))) unsigned int*)g,
                                     (__attribute__((address_space(3))) unsigned int*)l,
                                     16, 0, 0);
}

// ---------------- K1: WT[o][f] = bf16(W[f][o]) ----------------
__global__ __launch_bounds__(256) void k1_prep(const float* __restrict__ W,
                                               __bf16* __restrict__ WT) {
    int idx = blockIdx.x * 256 + threadIdx.x;   // 256 blocks -> 65536 = FD*FD
    int o = idx >> 8, f = idx & 255;
    WT[idx] = (__bf16)W[f * FD + o];
}

// ---------------- K2: Wh = x @ W (bf16 MFMA) ----------------
__global__ __launch_bounds__(256) void k2_whgemm(const float* __restrict__ x,
                                                 const __bf16* __restrict__ WT,
                                                 float* __restrict__ Wh) {
    const int wave = threadIdx.x >> 6;
    const int lane = threadIdx.x & 63;
    const int row0 = blockIdx.x * 32 + (wave >> 1) * 16;
    const int ohalf = (wave & 1) * 128;
    const int m = lane & 15;
    const int quad = lane >> 4;
    const int row = row0 + m;
    const float* xrow = x + (size_t)row * FD + quad * 8;

    f32x4 acc[8];
#pragma unroll
    for (int n = 0; n < 8; ++n) acc[n] = (f32x4){0.f, 0.f, 0.f, 0.f};

    for (int k0 = 0; k0 < FD; k0 += 32) {
        float4 xa = *(const float4*)(xrow + k0);
        float4 xb = *(const float4*)(xrow + k0 + 4);
        bf16x8 af;
        af[0] = (__bf16)xa.x; af[1] = (__bf16)xa.y; af[2] = (__bf16)xa.z; af[3] = (__bf16)xa.w;
        af[4] = (__bf16)xb.x; af[5] = (__bf16)xb.y; af[6] = (__bf16)xb.z; af[7] = (__bf16)xb.w;
#pragma unroll
        for (int n = 0; n < 8; ++n) {
            int o = ohalf + n * 16 + m;
            bf16x8 bf = *(const bf16x8*)(WT + o * FD + k0 + quad * 8);
            acc[n] = __builtin_amdgcn_mfma_f32_16x16x32_bf16(af, bf, acc[n], 0, 0, 0);
        }
    }
#pragma unroll
    for (int n = 0; n < 8; ++n) {
        int o = ohalf + n * 16 + m;
#pragma unroll
        for (int r = 0; r < 4; ++r) {
            Wh[(size_t)(row0 + quad * 4 + r) * FD + o] = acc[n][r];
        }
    }
}

// ---------------- K3: s_src / s_dst ----------------
__global__ __launch_bounds__(256) void k3_scores(const float* __restrict__ Wh,
                                                 const float* __restrict__ a_w,
                                                 float* __restrict__ s_src,
                                                 float* __restrict__ s_dst) {
    int wave = threadIdx.x >> 6, lane = threadIdx.x & 63;
    int row = blockIdx.x * 4 + wave;
    float4 wv = *(const float4*)(Wh + (size_t)row * FD + lane * 4);
    float4 a0 = *(const float4*)(a_w + lane * 4);
    float4 a1 = *(const float4*)(a_w + FD + lane * 4);
    float d0 = wv.x * a0.x + wv.y * a0.y + wv.z * a0.z + wv.w * a0.w;
    float d1 = wv.x * a1.x + wv.y * a1.y + wv.z * a1.z + wv.w * a1.w;
#pragma unroll
    for (int off = 32; off; off >>= 1) {
        d0 += __shfl_down(d0, off, 64);
        d1 += __shfl_down(d1, off, 64);
    }
    if (lane == 0) { s_src[row] = d0; s_dst[row] = d1; }
}

// ---------------- K4: P[b][i][j] = bf16(A*exp(lrelu(e))), den_part partial sums ----
// grid 1024: b = blk&7, jhalf = (blk>>3)&1, isp = blk>>4 (0..63); 32 i x 1024 j per block
__global__ __launch_bounds__(256) void k4_den(const float* __restrict__ A,
                                              const float* __restrict__ s_src,
                                              const float* __restrict__ s_dst,
                                              const float* __restrict__ a_bp,
                                              float* __restrict__ den_part,
                                              __bf16* __restrict__ P) {
    const int blk = blockIdx.x;
    const int b = blk & 7;
    const int jhalf = (blk >> 3) & 1;
    const int isp = blk >> 4;
    const int i0 = isp * 32;
    const int j = jhalf * 1024 + threadIdx.x * 4;
    __shared__ float ss[32];
    if (threadIdx.x < 32) ss[threadIdx.x] = s_src[b * NN + i0 + threadIdx.x] + a_bp[0];
    __syncthreads();
    float4 sd = *(const float4*)(s_dst + b * NN + j);
    float ax = 0.f, ay = 0.f, az = 0.f, aw = 0.f;
    const float* Ap = A + ((size_t)b * NN + i0) * NN + j;
    __bf16* Pp = P + ((size_t)b * NN + i0) * NN + j;
#pragma unroll 8
    for (int i = 0; i < 32; ++i) {
        float4 a = *(const float4*)(Ap + (size_t)i * NN);
        float si = ss[i];
        float e0 = si + sd.x; e0 = e0 > 0.f ? e0 : NEG_SLOPE * e0;
        float e1 = si + sd.y; e1 = e1 > 0.f ? e1 : NEG_SLOPE * e1;
        float e2 = si + sd.z; e2 = e2 > 0.f ? e2 : NEG_SLOPE * e2;
        float e3 = si + sd.w; e3 = e3 > 0.f ? e3 : NEG_SLOPE * e3;
        float p0 = a.x * __expf(e0);
        float p1 = a.y * __expf(e1);
        float p2 = a.z * __expf(e2);
        float p3 = a.w * __expf(e3);
        ax += p0; ay += p1; az += p2; aw += p3;
        bf16x4 pv;
        pv[0] = (__bf16)p0; pv[1] = (__bf16)p1; pv[2] = (__bf16)p2; pv[3] = (__bf16)p3;
        *(bf16x4*)(Pp + (size_t)i * NN) = pv;
    }
    float4 r = (float4){ax, ay, az, aw};
    *(float4*)(den_part + (size_t)isp * (BB * NN) + b * NN + j) = r;
}

// ---------------- K5: WhT[b][o][j] = bf16( Wh[b][j][o] / (sum(den_part)+eps) ) ----
__global__ __launch_bounds__(256) void k5_wht(const float* __restrict__ Wh,
                                              const float* __restrict__ den_part,
                                              __bf16* __restrict__ WhT) {
    const int b = blockIdx.z;
    const int j0 = blockIdx.x * 64;
    const int o0 = blockIdx.y * 64;
    __shared__ float tile[64][65];
    __shared__ float invd[64];
    if (threadIdx.x < 64) {
        float s = 0.f;
        const float* dp = den_part + b * NN + j0 + threadIdx.x;
#pragma unroll 8
        for (int sI = 0; sI < 64; ++sI) s += dp[(size_t)sI * (BB * NN)];
        invd[threadIdx.x] = 1.f / (s + EPSV);
    }
    __syncthreads();
    int jr = threadIdx.x >> 4, oc = (threadIdx.x & 15) * 4;
#pragma unroll
    for (int p = 0; p < 4; ++p) {
        int jj = jr + p * 16;
        float4 v = *(const float4*)(Wh + (size_t)(b * NN + j0 + jj) * FD + o0 + oc);
        float s = invd[jj];
        tile[jj][oc + 0] = v.x * s;
        tile[jj][oc + 1] = v.y * s;
        tile[jj][oc + 2] = v.z * s;
        tile[jj][oc + 3] = v.w * s;
    }
    __syncthreads();
    int ow = threadIdx.x >> 4, jc = (threadIdx.x & 15) * 4;
#pragma unroll
    for (int p = 0; p < 4; ++p) {
        int o = ow + p * 16;
        bf16x4 wv;
        wv[0] = (__bf16)tile[jc + 0][o];
        wv[1] = (__bf16)tile[jc + 1][o];
        wv[2] = (__bf16)tile[jc + 2][o];
        wv[3] = (__bf16)tile[jc + 3][o];
        *(bf16x4*)(WhT + (size_t)(b * FD + o0 + o) * NN + j0 + jc) = wv;
    }
}

// ---------------- K6: pure bf16 GEMM part[jsp] = P @ WhT^T (both K-contiguous) ----
// 512 blocks: b=blk&7 (XCD affinity for WhT), itile=(blk>>3)&15, jsp=blk>>7.
// 512 threads = 8 waves (2 wrow x 4 wcol); block tile 128i x 256o, BK=32, K-range 512.
// Operands staged via async global_load_lds (16B), double-buffered, 1 barrier/step.
__global__ __launch_bounds__(512, 4) void k6_out(const __bf16* __restrict__ P,
                                                 const __bf16* __restrict__ WhT,
                                                 float* __restrict__ part) {
    __shared__ __bf16 Pt[2][128 * 32];   // 2 x 8 KiB
    __shared__ __bf16 Bt[2][256 * 32];   // 2 x 16 KiB
    const int blk = blockIdx.x;
    const int b = blk & 7;
    const int r_ = blk >> 3;
    const int itile = r_ & 15;
    const int jsp = r_ >> 4;
    const int i0 = itile * 128;
    const int jbase = jsp * 512;
    const int t = threadIdx.x;
    const int w = t >> 6, lane = t & 63;
    const int wrow = w >> 2, wcol = w & 3;
    const int m = lane & 15, quad = lane >> 4;

    // staging roles: thread t -> row t>>2 (0..127), 16B chunk t&3
    const int srow = t >> 2, schunk = t & 3;
    const __bf16* gP  = P   + ((size_t)(b * NN + i0 + srow)) * NN + jbase + schunk * 8;
    const __bf16* gB0 = WhT + ((size_t)(b * FD + srow)) * NN + jbase + schunk * 8;
    const __bf16* gB1 = WhT + ((size_t)(b * FD + 128 + srow)) * NN + jbase + schunk * 8;
    __bf16* lP  = &Pt[0][(w * 16) * 32];          // wave-uniform LDS bases
    __bf16* lB0 = &Bt[0][(w * 16) * 32];
    __bf16* lB1 = &Bt[0][(128 + w * 16) * 32];
    const int lstep = 128 * 32;                    // buf1 offset (elems) for Pt
    const int lstepB = 256 * 32;

    // stage K-step 0 into buf 0
    gload16(gP, lP);
    gload16(gB0, lB0);
    gload16(gB1, lB1);

    f32x4 acc[4][4];
#pragma unroll
    for (int r = 0; r < 4; ++r)
#pragma unroll
        for (int n = 0; n < 4; ++n) acc[r][n] = (f32x4){0.f, 0.f, 0.f, 0.f};

    const __bf16* Pr = &Pt[0][(wrow * 64 + m) * 32 + quad * 8];
    const __bf16* Br = &Bt[0][(wcol * 64 + m) * 32 + quad * 8];

    for (int kk = 0; kk < 16; ++kk) {
        __syncthreads();   // buf (kk&1) fully staged; prev reads already in regs
        if (kk < 15) {     // async-stage next step into the other buffer
            int nb = (kk + 1) & 1;
            gload16(gP  + (kk + 1) * 32, lP  + nb * lstep);
            gload16(gB0 + (kk + 1) * 32, lB0 + nb * lstepB);
            gload16(gB1 + (kk + 1) * 32, lB1 + nb * lstepB);
        }
        const __bf16* Pk = Pr + (kk & 1) * lstep;
        const __bf16* Bk = Br + (kk & 1) * lstepB;
        bf16x8 af[4];
#pragma unroll
        for (int r = 0; r < 4; ++r) af[r] = *(const bf16x8*)(Pk + r * 16 * 32);
#pragma unroll
        for (int n = 0; n < 4; ++n) {
            bf16x8 bfr = *(const bf16x8*)(Bk + n * 16 * 32);
#pragma unroll
            for (int r = 0; r < 4; ++r)
                acc[r][n] = __builtin_amdgcn_mfma_f32_16x16x32_bf16(af[r], bfr, acc[r][n], 0, 0, 0);
        }
    }

    float* pout = part + (size_t)jsp * (BB * NN * FD);
#pragma unroll
    for (int r = 0; r < 4; ++r) {
#pragma unroll
        for (int n = 0; n < 4; ++n) {
            int o = wcol * 64 + n * 16 + m;
#pragma unroll
            for (int rr = 0; rr < 4; ++rr) {
                int row = i0 + wrow * 64 + r * 16 + quad * 4 + rr;
                pout[(size_t)(b * NN + row) * FD + o] = acc[r][n][rr];
            }
        }
    }
}

// ---------------- K7: out = sum of 4 jsplit partials ----------------
__global__ __launch_bounds__(256) void k7_reduce(const float4* __restrict__ part4,
                                                 float4* __restrict__ out4) {
    int idx = blockIdx.x * 256 + threadIdx.x;   // 4096 blocks -> 1,048,576 float4
    float4 a = part4[idx];
    float4 b2 = part4[idx + 1048576];
    float4 c = part4[idx + 2097152];
    float4 d = part4[idx + 3145728];
    float4 r;
    r.x = a.x + b2.x + c.x + d.x;
    r.y = a.y + b2.y + c.y + d.y;
    r.z = a.z + b2.z + c.z + d.z;
    r.w = a.w + b2.w + c.w + d.w;
    out4[idx] = r;
}

extern "C" void kernel_launch(void* const* d_in, const int* in_sizes, int n_in,
                              void* d_out, int out_size, void* d_ws, size_t ws_size,
                              hipStream_t stream) {
    const float* A   = (const float*)d_in[0];
    const float* x   = (const float*)d_in[1];
    const float* W   = (const float*)d_in[2];
    const float* a_w = (const float*)d_in[3];
    const float* a_b = (const float*)d_in[4];
    float* out = (float*)d_out;

    char* ws = (char*)d_ws;
    __bf16* WT      = (__bf16*)ws;                      // 131,072 B
    float*  Wh      = (float*)(ws + 131072);            // 16,777,216 B
    __bf16* WhT     = (__bf16*)(ws + 16908288);         // 8,388,608 B
    float*  s_src   = (float*)(ws + 25296896);          // 65,536 B
    float*  s_dst   = (float*)(ws + 25362432);          // 65,536 B
    float*  den_part= (float*)(ws + 25427968);          // 64*16384*4 = 4,194,304 B
    __bf16* P       = (__bf16*)(ws + 29622272);         // 8*2048*2048*2 = 67,108,864 B
    float*  part    = (float*)(ws + 96731136);          // 4*16,777,216 = 67,108,864 B
                                                        // total = 163,840,000 B

    k1_prep<<<256, 256, 0, stream>>>(W, WT);
    k2_whgemm<<<512, 256, 0, stream>>>(x, WT, Wh);
    k3_scores<<<4096, 256, 0, stream>>>(Wh, a_w, s_src, s_dst);
    k4_den<<<1024, 256, 0, stream>>>(A, s_src, s_dst, a_b, den_part, P);
    k5_wht<<<dim3(32, 4, 8), 256, 0, stream>>>(Wh, den_part, WhT);
    k6_out<<<512, 512, 0, stream>>>(P, WhT, part);
    k7_reduce<<<4096, 256, 0, stream>>>((const float4*)part, (float4*)out);
}